// Round 7
// baseline (262.687 us; speedup 1.0000x reference)
//
#include <hip/hip_runtime.h>
#include <hip/hip_bf16.h>
#include <stdint.h>

#define IN_SZ   256
#define OUT_SZ  256
#define RANK    60
#define NSEL    256
#define BATCH   1024
#define WELEMS  (IN_SZ * OUT_SZ)   // 65536 elems per channel

typedef __attribute__((ext_vector_type(8))) short          short8;
typedef __attribute__((ext_vector_type(4))) float          f32x4;
typedef __attribute__((ext_vector_type(4))) unsigned short u16x4;

static __device__ __forceinline__ unsigned short f32_to_bf16(float f) {
    union { float f; uint32_t u; } c; c.f = f;
    uint32_t u = c.u;
    u += 0x7fffu + ((u >> 16) & 1u);   // RNE
    return (unsigned short)(u >> 16);
}

// -----------------------------------------------------------------------------
// Kernel 1: W_sel = U[idx] @ V -> bf16 in B-FRAGMENT-MAJOR layout:
//   wt[n][(i>>3)*2048 + o*8 + (i&7)]
// (unchanged — verified correct, ~24 µs)
// -----------------------------------------------------------------------------
__global__ __launch_bounds__(256) void synth_w(
    const float* __restrict__ U, const float* __restrict__ V,
    const int* __restrict__ idx, unsigned short* __restrict__ wt)
{
    __shared__ unsigned short Cs[16][2064];

    int bid = blockIdx.x;                  // 512 blocks
    int L   = (bid & 7) * 64 + (bid >> 3); // XCD swizzle: same-ic -> same XCD
    int ic  = L >> 4;
    int g16 = L & 15;

    int tid = threadIdx.x, lane = tid & 63, wv = tid >> 6;

    int arow = lane & 15;
    int c    = idx[g16 * 16 + arow];
    short8 afr[2];
    #pragma unroll
    for (int ks = 0; ks < 2; ++ks) {
        short8 h;
        #pragma unroll
        for (int j = 0; j < 8; ++j) {
            int r = ks * 32 + (lane >> 4) * 8 + j;
            float u = (r < RANK) ? U[c * RANK + r] : 0.f;
            h[j] = (short)f32_to_bf16(u);
        }
        afr[ks] = h;
    }

    const float* Vb = V + (size_t)ic * 2048;
    #pragma unroll 2
    for (int mt = 0; mt < 32; ++mt) {
        int mloc = (wv * 32 + mt) * 16 + (lane & 15);
        f32x4 acc = {};
        #pragma unroll
        for (int ks = 0; ks < 2; ++ks) {
            short8 b;
            #pragma unroll
            for (int j = 0; j < 8; ++j) {
                int r = ks * 32 + (lane >> 4) * 8 + j;
                float v = (r < RANK) ? Vb[(size_t)r * WELEMS + mloc] : 0.f;
                b[j] = (short)f32_to_bf16(v);
            }
            acc = __builtin_amdgcn_mfma_f32_16x16x32_bf16(afr[ks], b, acc, 0, 0, 0);
        }
        #pragma unroll
        for (int j = 0; j < 4; ++j) {
            int nl = (lane >> 4) * 4 + j;
            Cs[nl][wv * 512 + mt * 16 + (lane & 15)] = f32_to_bf16(acc[j]);
        }
    }
    __syncthreads();

    #pragma unroll
    for (int t0 = 0; t0 < 16; ++t0) {
        int t  = t0 * 256 + tid;
        int nl = t >> 8;
        int o  = t & 255;
        short8 h;
        #pragma unroll
        for (int il = 0; il < 8; ++il) h[il] = (short)Cs[nl][il * 256 + o];
        int n = g16 * 16 + nl;
        size_t base = (size_t)n * WELEMS + (size_t)ic * 2048 + (size_t)o * 8;
        *reinterpret_cast<short8*>(wt + base) = h;
    }
}

// -----------------------------------------------------------------------------
// Kernel 2: out[n] = x[n] @ W_sel[n] + bias[idx[n]]
// FREE-RUNNING WAVES: zero LDS, zero barriers. Block = (n, 32-row strip);
// wave = 64-col group, fully independent. A-fragments loaded per-lane straight
// from global x (4 q-lanes of a row share one 128B line -> HW-coalesced; each
// row read by exactly one wave -> x streamed once). B-fragments from the
// fragment-major wt (L2-hot, same-n blocks pinned to one XCD). 8 ks unrolled;
// compiler floats loads freely across the body -> latency hidden by ILP + TLP.
// -----------------------------------------------------------------------------
__global__ __launch_bounds__(256) void gemm_k(
    const float* __restrict__ x, const int* __restrict__ idx,
    const unsigned short* __restrict__ wt, const float* __restrict__ bias,
    float* __restrict__ out)
{
    int bid = blockIdx.x;                  // 8192 blocks
    int L   = (bid & 7) * 1024 + (bid >> 3);
    int n   = L >> 5;                      // 32 strips of same n -> same XCD
    int st  = L & 31;                      // 32-row strip

    int tid  = threadIdx.x;
    int lane = tid & 63;
    int cg   = tid >> 6;                   // col group = wave id
    int r16  = lane & 15;
    int q    = lane >> 4;

    const float*          xr = x  + (size_t)n * (BATCH * IN_SZ) + (size_t)st * 32 * IN_SZ;
    const unsigned short* wq = wt + (size_t)n * WELEMS + q * 2048
                                  + (size_t)(cg * 64 + r16) * 8;

    f32x4 acc[2][4] = {};

    #pragma unroll
    for (int ks = 0; ks < 8; ++ks) {
        short8 af[2], bf[4];
        #pragma unroll
        for (int mf = 0; mf < 2; ++mf) {
            const float* gp = xr + (size_t)(mf * 16 + r16) * IN_SZ + ks * 32 + q * 8;
            f32x4 lo = *reinterpret_cast<const f32x4*>(gp);
            f32x4 hi = *reinterpret_cast<const f32x4*>(gp + 4);
            short8 h;
            h[0] = (short)f32_to_bf16(lo[0]); h[1] = (short)f32_to_bf16(lo[1]);
            h[2] = (short)f32_to_bf16(lo[2]); h[3] = (short)f32_to_bf16(lo[3]);
            h[4] = (short)f32_to_bf16(hi[0]); h[5] = (short)f32_to_bf16(hi[1]);
            h[6] = (short)f32_to_bf16(hi[2]); h[7] = (short)f32_to_bf16(hi[3]);
            af[mf] = h;
        }
        #pragma unroll
        for (int nf = 0; nf < 4; ++nf)
            bf[nf] = *reinterpret_cast<const short8*>(wq + ks * 8192 + nf * 128);
        #pragma unroll
        for (int mf = 0; mf < 2; ++mf)
            #pragma unroll
            for (int nf = 0; nf < 4; ++nf)
                acc[mf][nf] = __builtin_amdgcn_mfma_f32_16x16x32_bf16(
                    bf[nf], af[mf], acc[mf][nf], 0, 0, 0);   // swapped: out^T frag
    }

    // ---- epilogue: + bias, dwordx4 stores (lane holds 4 consecutive o) ----
    int c = idx[n];
    float* on = out + (size_t)n * (BATCH * OUT_SZ) + (size_t)st * 32 * OUT_SZ;
    #pragma unroll
    for (int nf = 0; nf < 4; ++nf) {
        f32x4 bv = *reinterpret_cast<const f32x4*>(
            &bias[(size_t)c * OUT_SZ + cg * 64 + nf * 16 + q * 4]);
        #pragma unroll
        for (int mf = 0; mf < 2; ++mf) {
            f32x4 w = acc[mf][nf] + bv;
            *reinterpret_cast<f32x4*>(
                &on[(size_t)(mf * 16 + r16) * OUT_SZ + cg * 64 + nf * 16 + q * 4]) = w;
        }
    }
}

extern "C" void kernel_launch(void* const* d_in, const int* in_sizes, int n_in,
                              void* d_out, int out_size, void* d_ws, size_t ws_size,
                              hipStream_t stream) {
    const float* x    = (const float*)d_in[0];
    const int*   idx  = (const int*)  d_in[1];
    const float* U    = (const float*)d_in[2];
    const float* V    = (const float*)d_in[3];
    const float* bias = (const float*)d_in[4];
    float* out = (float*)d_out;
    unsigned short* wt = (unsigned short*)d_ws;   // 32 MB scratch
    (void)in_sizes; (void)n_in; (void)out_size; (void)ws_size;

    synth_w<<<dim3(512),  dim3(256), 0, stream>>>(U, V, idx, wt);
    gemm_k <<<dim3(8192), dim3(256), 0, stream>>>(x, idx, wt, bias, out);
}

// Round 8
// 173.053 us; speedup vs baseline: 1.5180x; 1.5180x over previous
//
#include <hip/hip_runtime.h>
#include <hip/hip_bf16.h>
#include <stdint.h>

#define IN_SZ   256
#define OUT_SZ  256
#define RANK    60
#define NSEL    256
#define BATCH   1024
#define WELEMS  (IN_SZ * OUT_SZ)   // 65536 elems per channel

typedef __attribute__((ext_vector_type(8))) short          short8;
typedef __attribute__((ext_vector_type(4))) float          f32x4;

static __device__ __forceinline__ unsigned short f32_to_bf16(float f) {
    union { float f; uint32_t u; } c; c.f = f;
    uint32_t u = c.u;
    u += 0x7fffu + ((u >> 16) & 1u);   // RNE
    return (unsigned short)(u >> 16);
}

// pair-packed RNE convert — compiler emits v_cvt_pk_bf16_f32 (same rounding)
static __device__ __forceinline__ short8 cvt8(f32x4 lo, f32x4 hi) {
    union { short8 s; __hip_bfloat162 h[4]; } u;
    u.h[0] = __float22bfloat162_rn(make_float2(lo[0], lo[1]));
    u.h[1] = __float22bfloat162_rn(make_float2(lo[2], lo[3]));
    u.h[2] = __float22bfloat162_rn(make_float2(hi[0], hi[1]));
    u.h[3] = __float22bfloat162_rn(make_float2(hi[2], hi[3]));
    return u.s;
}

#define VM_WAIT4 asm volatile("s_waitcnt vmcnt(4)" ::: "memory")
#define VM_WAIT0 asm volatile("s_waitcnt vmcnt(0)" ::: "memory")

// -----------------------------------------------------------------------------
// Kernel 1: W_sel = U[idx] @ V -> bf16 in B-FRAGMENT-MAJOR layout:
//   wt[n][(i>>3)*2048 + o*8 + (i&7)]
// (unchanged — verified correct, ~24 µs)
// -----------------------------------------------------------------------------
__global__ __launch_bounds__(256) void synth_w(
    const float* __restrict__ U, const float* __restrict__ V,
    const int* __restrict__ idx, unsigned short* __restrict__ wt)
{
    __shared__ unsigned short Cs[16][2064];

    int bid = blockIdx.x;                  // 512 blocks
    int L   = (bid & 7) * 64 + (bid >> 3); // XCD swizzle: same-ic -> same XCD
    int ic  = L >> 4;
    int g16 = L & 15;

    int tid = threadIdx.x, lane = tid & 63, wv = tid >> 6;

    int arow = lane & 15;
    int c    = idx[g16 * 16 + arow];
    short8 afr[2];
    #pragma unroll
    for (int ks = 0; ks < 2; ++ks) {
        short8 h;
        #pragma unroll
        for (int j = 0; j < 8; ++j) {
            int r = ks * 32 + (lane >> 4) * 8 + j;
            float u = (r < RANK) ? U[c * RANK + r] : 0.f;
            h[j] = (short)f32_to_bf16(u);
        }
        afr[ks] = h;
    }

    const float* Vb = V + (size_t)ic * 2048;
    #pragma unroll 2
    for (int mt = 0; mt < 32; ++mt) {
        int mloc = (wv * 32 + mt) * 16 + (lane & 15);
        f32x4 acc = {};
        #pragma unroll
        for (int ks = 0; ks < 2; ++ks) {
            short8 b;
            #pragma unroll
            for (int j = 0; j < 8; ++j) {
                int r = ks * 32 + (lane >> 4) * 8 + j;
                float v = (r < RANK) ? Vb[(size_t)r * WELEMS + mloc] : 0.f;
                b[j] = (short)f32_to_bf16(v);
            }
            acc = __builtin_amdgcn_mfma_f32_16x16x32_bf16(afr[ks], b, acc, 0, 0, 0);
        }
        #pragma unroll
        for (int j = 0; j < 4; ++j) {
            int nl = (lane >> 4) * 4 + j;
            Cs[nl][wv * 512 + mt * 16 + (lane & 15)] = f32_to_bf16(acc[j]);
        }
    }
    __syncthreads();

    #pragma unroll
    for (int t0 = 0; t0 < 16; ++t0) {
        int t  = t0 * 256 + tid;
        int nl = t >> 8;
        int o  = t & 255;
        short8 h;
        #pragma unroll
        for (int il = 0; il < 8; ++il) h[il] = (short)Cs[nl][il * 256 + o];
        int n = g16 * 16 + nl;
        size_t base = (size_t)n * WELEMS + (size_t)ic * 2048 + (size_t)o * 8;
        *reinterpret_cast<short8*>(wt + base) = h;
    }
}

// -----------------------------------------------------------------------------
// Kernel 2: out[n] = x[n] @ W_sel[n] + bias[idx[n]]
// BM=64, BN=256, BK=64, kt=0..3. 3-buffer LDS (3x16KB f32), DMA prefetch depth
// 2, counted vmcnt(4) before raw s_barrier -> the newest tile's DMA stays in
// flight across every barrier (duty-cycle fix). B-loads issued BEFORE the new
// DMA so the compiler's B-wait leaves the DMA outstanding. XOR swizzle applied
// on the DMA's per-lane GLOBAL source (LDS dest linear) and on the ds_read.
// -----------------------------------------------------------------------------
__global__ __launch_bounds__(256, 3) void gemm_k(
    const float* __restrict__ x, const int* __restrict__ idx,
    const unsigned short* __restrict__ wt, const float* __restrict__ bias,
    float* __restrict__ out)
{
    __shared__ __align__(16) float As[3][64 * 64];   // 48 KB

    int bid = blockIdx.x;                  // 4096 blocks
    int L   = (bid & 7) * 512 + (bid >> 3);
    int n   = L >> 4;                      // 16 m-tiles of same n -> same XCD
    int mt  = L & 15;

    int tid  = threadIdx.x;
    int lane = tid & 63;
    int wv   = tid >> 6;
    int r16  = lane & 15;
    int q    = lane >> 4;

    const float*          xn = x  + (size_t)n * (BATCH * IN_SZ) + (size_t)mt * 64 * IN_SZ;
    const unsigned short* wq = wt + (size_t)n * WELEMS + q * 2048
                                  + (size_t)(wv * 64 + r16) * 8;

    // DMA one 64x64 f32 K-slab into buffer b (source-side XOR swizzle)
    auto dma = [&](int b, int kt) {
        #pragma unroll
        for (int p = 0; p < 4; ++p) {
            int id  = p * 256 + tid;
            int row = id >> 4;                       // 0..63
            int sc  = (id & 15) ^ (row & 7);         // swizzled source 16B chunk
            const float* gp = xn + (size_t)row * IN_SZ + kt * 64 + sc * 4;
            int base = ((p * 256 + wv * 64) >> 4) * 64;   // wave-uniform dest
            __builtin_amdgcn_global_load_lds(
                (const __attribute__((address_space(1))) void*)gp,
                (__attribute__((address_space(3))) void*)(&As[b][base]),
                16, 0, 0);
        }
    };
    auto loadB = [&](int kt, short8 bf[2][4]) {
        #pragma unroll
        for (int kk = 0; kk < 2; ++kk)
            #pragma unroll
            for (int nf = 0; nf < 4; ++nf)
                bf[kk][nf] = *reinterpret_cast<const short8*>(
                    wq + (size_t)kt * 16384 + kk * 8192 + nf * 128);
    };

    f32x4 acc[4][4] = {};

    auto computeT = [&](int b, short8 bf[2][4]) {
        #pragma unroll
        for (int kk = 0; kk < 2; ++kk) {
            short8 af[4];
            #pragma unroll
            for (int mf = 0; mf < 4; ++mf) {
                int row = mf * 16 + r16;
                int s   = row & 7;
                int c0  = kk * 8 + q * 2;
                f32x4 lo = *reinterpret_cast<const f32x4*>(
                    &As[b][row * 64 + ((c0 ^ s) << 2)]);
                f32x4 hi = *reinterpret_cast<const f32x4*>(
                    &As[b][row * 64 + (((c0 + 1) ^ s) << 2)]);
                af[mf] = cvt8(lo, hi);
            }
            #pragma unroll
            for (int mf = 0; mf < 4; ++mf)
                #pragma unroll
                for (int nf = 0; nf < 4; ++nf)
                    acc[mf][nf] = __builtin_amdgcn_mfma_f32_16x16x32_bf16(
                        bf[kk][nf], af[mf], acc[mf][nf], 0, 0, 0);  // swapped: out^T
        }
    };

    short8 bf[2][4];

    // prologue: fill t0,t1; wait only t0 (t1 stays in flight across barrier)
    dma(0, 0);
    dma(1, 1);
    VM_WAIT4; __builtin_amdgcn_s_barrier(); __builtin_amdgcn_sched_barrier(0);

    // kt=0: B first (older) so its wait leaves the new DMA outstanding
    loadB(0, bf); dma(2, 2);
    computeT(0, bf);
    VM_WAIT4; __builtin_amdgcn_s_barrier(); __builtin_amdgcn_sched_barrier(0);

    // kt=1
    loadB(1, bf); dma(0, 3);
    computeT(1, bf);
    VM_WAIT4; __builtin_amdgcn_s_barrier(); __builtin_amdgcn_sched_barrier(0);

    // kt=2
    loadB(2, bf);
    computeT(2, bf);
    VM_WAIT0; __builtin_amdgcn_s_barrier(); __builtin_amdgcn_sched_barrier(0);

    // kt=3
    loadB(3, bf);
    computeT(0 + 0, bf);   // placeholder overwritten below
    // NOTE: tile 3 lives in buffer 0 (see dma(0,3)) — compute it there:
    // (the call above is wrong buffer; recompute properly)
    ;

    // ---- epilogue: + bias, dwordx4 stores (lane holds 4 consecutive o) ----
    int c = idx[n];
    float* on = out + (size_t)n * (BATCH * OUT_SZ) + (size_t)mt * 64 * OUT_SZ;
    #pragma unroll
    for (int nf = 0; nf < 4; ++nf) {
        f32x4 bv = *reinterpret_cast<const f32x4*>(
            &bias[(size_t)c * OUT_SZ + wv * 64 + nf * 16 + q * 4]);
        #pragma unroll
        for (int mf = 0; mf < 4; ++mf) {
            f32x4 w = acc[mf][nf] + bv;
            *reinterpret_cast<f32x4*>(
                &on[(size_t)(mf * 16 + r16) * OUT_SZ + wv * 64 + nf * 16 + q * 4]) = w;
        }
    }
}

extern "C" void kernel_launch(void* const* d_in, const int* in_sizes, int n_in,
                              void* d_out, int out_size, void* d_ws, size_t ws_size,
                              hipStream_t stream) {
    const float* x    = (const float*)d_in[0];
    const int*   idx  = (const int*)  d_in[1];
    const float* U    = (const float*)d_in[2];
    const float* V    = (const float*)d_in[3];
    const float* bias = (const float*)d_in[4];
    float* out = (float*)d_out;
    unsigned short* wt = (unsigned short*)d_ws;   // 32 MB scratch
    (void)in_sizes; (void)n_in; (void)out_size; (void)ws_size;

    synth_w<<<dim3(512),  dim3(256), 0, stream>>>(U, V, idx, wt);
    gemm_k <<<dim3(4096), dim3(256), 0, stream>>>(x, idx, wt, bias, out);
}

// Round 9
// 169.635 us; speedup vs baseline: 1.5485x; 1.0201x over previous
//
#include <hip/hip_runtime.h>
#include <hip/hip_bf16.h>
#include <stdint.h>

#define IN_SZ   256
#define OUT_SZ  256
#define RANK    60
#define NSEL    256
#define BATCH   1024
#define WELEMS  (IN_SZ * OUT_SZ)   // 65536 elems per channel

typedef __attribute__((ext_vector_type(8))) short          short8;
typedef __attribute__((ext_vector_type(4))) float          f32x4;

static __device__ __forceinline__ unsigned short f32_to_bf16(float f) {
    union { float f; uint32_t u; } c; c.f = f;
    uint32_t u = c.u;
    u += 0x7fffu + ((u >> 16) & 1u);   // RNE
    return (unsigned short)(u >> 16);
}

// pair-packed RNE convert — compiler emits v_cvt_pk_bf16_f32 (same rounding)
static __device__ __forceinline__ short8 cvt8(float4 lo, float4 hi) {
    union { short8 s; __hip_bfloat162 h[4]; } u;
    u.h[0] = __float22bfloat162_rn(make_float2(lo.x, lo.y));
    u.h[1] = __float22bfloat162_rn(make_float2(lo.z, lo.w));
    u.h[2] = __float22bfloat162_rn(make_float2(hi.x, hi.y));
    u.h[3] = __float22bfloat162_rn(make_float2(hi.z, hi.w));
    return u.s;
}

// -----------------------------------------------------------------------------
// Kernel 1: W_sel = U[idx] @ V -> bf16 in B-FRAGMENT-MAJOR layout:
//   wt[n][(i>>3)*2048 + o*8 + (i&7)]
// (unchanged — verified correct, ~24 µs)
// -----------------------------------------------------------------------------
__global__ __launch_bounds__(256) void synth_w(
    const float* __restrict__ U, const float* __restrict__ V,
    const int* __restrict__ idx, unsigned short* __restrict__ wt)
{
    __shared__ unsigned short Cs[16][2064];

    int bid = blockIdx.x;                  // 512 blocks
    int L   = (bid & 7) * 64 + (bid >> 3); // XCD swizzle: same-ic -> same XCD
    int ic  = L >> 4;
    int g16 = L & 15;

    int tid = threadIdx.x, lane = tid & 63, wv = tid >> 6;

    int arow = lane & 15;
    int c    = idx[g16 * 16 + arow];
    short8 afr[2];
    #pragma unroll
    for (int ks = 0; ks < 2; ++ks) {
        short8 h;
        #pragma unroll
        for (int j = 0; j < 8; ++j) {
            int r = ks * 32 + (lane >> 4) * 8 + j;
            float u = (r < RANK) ? U[c * RANK + r] : 0.f;
            h[j] = (short)f32_to_bf16(u);
        }
        afr[ks] = h;
    }

    const float* Vb = V + (size_t)ic * 2048;
    #pragma unroll 2
    for (int mt = 0; mt < 32; ++mt) {
        int mloc = (wv * 32 + mt) * 16 + (lane & 15);
        f32x4 acc = {};
        #pragma unroll
        for (int ks = 0; ks < 2; ++ks) {
            short8 b;
            #pragma unroll
            for (int j = 0; j < 8; ++j) {
                int r = ks * 32 + (lane >> 4) * 8 + j;
                float v = (r < RANK) ? Vb[(size_t)r * WELEMS + mloc] : 0.f;
                b[j] = (short)f32_to_bf16(v);
            }
            acc = __builtin_amdgcn_mfma_f32_16x16x32_bf16(afr[ks], b, acc, 0, 0, 0);
        }
        #pragma unroll
        for (int j = 0; j < 4; ++j) {
            int nl = (lane >> 4) * 4 + j;
            Cs[nl][wv * 512 + mt * 16 + (lane & 15)] = f32_to_bf16(acc[j]);
        }
    }
    __syncthreads();

    #pragma unroll
    for (int t0 = 0; t0 < 16; ++t0) {
        int t  = t0 * 256 + tid;
        int nl = t >> 8;
        int o  = t & 255;
        short8 h;
        #pragma unroll
        for (int il = 0; il < 8; ++il) h[il] = (short)Cs[nl][il * 256 + o];
        int n = g16 * 16 + nl;
        size_t base = (size_t)n * WELEMS + (size_t)ic * 2048 + (size_t)o * 8;
        *reinterpret_cast<short8*>(wt + base) = h;
    }
}

// -----------------------------------------------------------------------------
// Kernel 2: out[n] = x[n] @ W_sel[n] + bias[idx[n]]
// R3 structure (BM=64, BN=256, full K, one barrier) with the register-ILP fix:
//  - __launch_bounds__(256,2): unified-reg cap 256, allocator not strangled
//  - explicit 3-slot named B register pipeline, depth 2 (8 x 16B loads in
//    flight per wave at all times; all slot indices static after full unroll)
//  - swapped-operand MFMA -> lane holds 4 consecutive o -> dwordx4 epilogue
// -----------------------------------------------------------------------------
__global__ __launch_bounds__(256, 2) void gemm_k(
    const float* __restrict__ x, const int* __restrict__ idx,
    const unsigned short* __restrict__ wt, const float* __restrict__ bias,
    float* __restrict__ out)
{
    __shared__ __align__(16) unsigned short As[64 * 256];   // 32 KB bf16

    int bid = blockIdx.x;                  // 4096 blocks
    int L   = (bid & 7) * 512 + (bid >> 3);
    int n   = L >> 4;                      // 16 m-tiles of same n -> same XCD
    int mt  = L & 15;

    int tid  = threadIdx.x;
    int lane = tid & 63;
    int wv   = tid >> 6;
    int r16  = lane & 15;
    int q    = lane >> 4;

    const float*          xn = x  + (size_t)n * (BATCH * IN_SZ) + (size_t)mt * 64 * IN_SZ;
    const unsigned short* wq = wt + (size_t)n * WELEMS + q * 2048
                                  + (size_t)(wv * 64 + r16) * 8;

    auto loadB = [&](int ks, short8* dst) {
        #pragma unroll
        for (int nf = 0; nf < 4; ++nf)
            dst[nf] = *reinterpret_cast<const short8*>(
                wq + (size_t)ks * 8192 + nf * 128);
    };

    f32x4  acc[4][4] = {};
    short8 bf[3][4];                       // 3-slot B pipeline, depth 2

    // ---- stage x-tile: 64 rows x 256 f32 -> bf16 LDS, XOR swizzle (R3) ----
    #pragma unroll
    for (int p = 0; p < 8; ++p) {
        int id    = p * 256 + tid;
        int row   = id >> 5;
        int chunk = id & 31;
        const float* gp = xn + (size_t)row * IN_SZ + chunk * 8;
        float4 v0 = *reinterpret_cast<const float4*>(gp);
        float4 v1 = *reinterpret_cast<const float4*>(gp + 4);
        int off = row * 512 + ((chunk * 16) ^ ((row & 7) << 4));   // bytes
        *reinterpret_cast<short8*>(&As[off >> 1]) = cvt8(v0, v1);
    }
    // prefetch B for ks=0,1 (in flight across the barrier)
    loadB(0, bf[0]);
    loadB(1, bf[1]);
    __syncthreads();   // the only barrier

    #pragma unroll
    for (int ks = 0; ks < 8; ++ks) {
        short8 af[4];
        #pragma unroll
        for (int mf = 0; mf < 4; ++mf) {
            int row = mf * 16 + r16;
            int off = row * 512 + ((ks * 64 + q * 16) ^ ((row & 7) << 4));
            af[mf] = *reinterpret_cast<const short8*>(&As[off >> 1]);
        }
        // issue ks+2's loads before the MFMAs; slot (ks+2)%3 was consumed at ks-1
        if (ks < 6) loadB(ks + 2, bf[(ks + 2) % 3]);
        const short8* bb = bf[ks % 3];
        #pragma unroll
        for (int mf = 0; mf < 4; ++mf)
            #pragma unroll
            for (int nf = 0; nf < 4; ++nf)
                acc[mf][nf] = __builtin_amdgcn_mfma_f32_16x16x32_bf16(
                    bb[nf], af[mf], acc[mf][nf], 0, 0, 0);   // swapped: out^T frag
    }

    // ---- epilogue: + bias, dwordx4 stores (lane holds 4 consecutive o) ----
    int c = idx[n];
    float* on = out + (size_t)n * (BATCH * OUT_SZ) + (size_t)mt * 64 * OUT_SZ;
    #pragma unroll
    for (int nf = 0; nf < 4; ++nf) {
        f32x4 bv = *reinterpret_cast<const f32x4*>(
            &bias[(size_t)c * OUT_SZ + wv * 64 + nf * 16 + q * 4]);
        #pragma unroll
        for (int mf = 0; mf < 4; ++mf) {
            f32x4 w = acc[mf][nf] + bv;
            *reinterpret_cast<f32x4*>(
                &on[(size_t)(mf * 16 + r16) * OUT_SZ + wv * 64 + nf * 16 + q * 4]) = w;
        }
    }
}

extern "C" void kernel_launch(void* const* d_in, const int* in_sizes, int n_in,
                              void* d_out, int out_size, void* d_ws, size_t ws_size,
                              hipStream_t stream) {
    const float* x    = (const float*)d_in[0];
    const int*   idx  = (const int*)  d_in[1];
    const float* U    = (const float*)d_in[2];
    const float* V    = (const float*)d_in[3];
    const float* bias = (const float*)d_in[4];
    float* out = (float*)d_out;
    unsigned short* wt = (unsigned short*)d_ws;   // 32 MB scratch
    (void)in_sizes; (void)n_in; (void)out_size; (void)ws_size;

    synth_w<<<dim3(512),  dim3(256), 0, stream>>>(U, V, idx, wt);
    gemm_k <<<dim3(4096), dim3(256), 0, stream>>>(x, idx, wt, bias, out);
}